// Round 1
// baseline (277.323 us; speedup 1.0000x reference)
//
#include <hip/hip_runtime.h>

typedef _Float16 f16;
typedef _Float16 f16x4 __attribute__((ext_vector_type(4)));
typedef _Float16 f16x8 __attribute__((ext_vector_type(8)));
typedef float f32x4 __attribute__((ext_vector_type(4)));

// Problem constants: B=64, T=240, J=22, D=128, H=8, hd=16
// n_tokens = 15360, rows = n_tokens*22 = 337920
#define N_ROWS   337920
#define TPW      4              // tokens per workgroup
#define RG       88             // valid rows per group (TPW*22)
#define NGROUPS  3840           // 15360/TPW

// LDS: qkv [96 rows][256 f16] (cols 0-127 Q -> later y, cols 128-255 K), XOR-swizzled
//      vT  [128][104] f16 (V transposed, token-padded: col = t*24 + j)
#define QKV_ROWB   512
#define QKV_BYTES  (96 * QKV_ROWB)           // 49152
#define VT_STRIDE  104
#define LDS_BYTES  (QKV_BYTES + 128 * VT_STRIDE * 2)  // 49152 + 26624 = 75776

__device__ __forceinline__ uint32_t swz(int row, int bytecol) {
  return (uint32_t)((row * QKV_ROWB + bytecol) ^ ((row & 7) << 4));
}

__device__ __forceinline__ f16x8 pack8(float4 a, float4 b) {
  f16x8 r;
  r[0] = (f16)a.x; r[1] = (f16)a.y; r[2] = (f16)a.z; r[3] = (f16)a.w;
  r[4] = (f16)b.x; r[5] = (f16)b.y; r[6] = (f16)b.z; r[7] = (f16)b.w;
  return r;
}

__global__ __launch_bounds__(256, 2)
void mga_fused(const float* __restrict__ x, const int* __restrict__ adj,
               const float* __restrict__ wqkv, const float* __restrict__ bqkv,
               const float* __restrict__ wout, const float* __restrict__ bout,
               float* __restrict__ out) {
  __shared__ __align__(16) char smem[LDS_BYTES];
  char* qkvB = smem;
  f16* vT = (f16*)(smem + QKV_BYTES);

  const int tid  = threadIdx.x;
  const int wv   = tid >> 6;      // wave 0..3
  const int l    = tid & 63;
  const int g    = l >> 4;        // lane k-group 0..3
  const int r16  = l & 15;
  const long g0  = (long)blockIdx.x * RG;   // first global row of this group

  // ---- zero vT (so masked-out (P==0) lanes multiply finite zeros, never NaN) ----
  {
    int* p = (int*)vT;
    #pragma unroll
    for (int i = 0; i < 26; i++) p[tid + 256 * i] = 0;   // 26*256*4 = 26624 B
  }

  // ---- per-lane additive mask regs M^T[j][q]; j = jt*16+4g+r, q = qt*16+r16 ----
  float mreg[2][2][4];
  #pragma unroll
  for (int qt = 0; qt < 2; qt++)
    #pragma unroll
    for (int jt = 0; jt < 2; jt++)
      #pragma unroll
      for (int r = 0; r < 4; r++) {
        int q = qt * 16 + r16;
        int j = jt * 16 + 4 * g + r;
        float m = -1e30f;
        if (j < 22) {
          if (q >= 22) m = 0.0f;                       // garbage q rows: keep softmax finite
          else m = (adj[q * 22 + j] > 0) ? 0.0f : -1e30f;
        }
        mreg[qt][jt][r] = m;
      }

  __syncthreads();   // vT zeros visible before phase-1 vT writes

  // ============ Phase 1: QKV projection (wave wv owns n-tiles 6wv..6wv+5 of 24) ======
  // qkv[row][c] = sum_k x[row][k]*Wqkv[c][k] + b[c];  Q scaled by 0.25 here.
  f16x8 bfr[6][4];
  float bias[6];
  #pragma unroll
  for (int i = 0; i < 6; i++) {
    int nt = 6 * wv + i;
    int wrow = nt * 16 + r16;
    const float* wp = wqkv + wrow * 128 + g * 8;
    #pragma unroll
    for (int ks = 0; ks < 4; ks++) {
      float4 u0 = *(const float4*)(wp + ks * 32);
      float4 u1 = *(const float4*)(wp + ks * 32 + 4);
      bfr[i][ks] = pack8(u0, u1);
    }
    bias[i] = bqkv[wrow];
  }

  for (int mt = 0; mt < 6; mt++) {
    long rowg = g0 + mt * 16 + r16;
    if (rowg > (long)N_ROWS - 1) rowg = N_ROWS - 1;   // clamp pad rows of last group
    const float* xp = x + rowg * 128 + g * 8;
    f16x8 afr[4];
    #pragma unroll
    for (int ks = 0; ks < 4; ks++) {
      float4 u0 = *(const float4*)(xp + ks * 32);
      float4 u1 = *(const float4*)(xp + ks * 32 + 4);
      afr[ks] = pack8(u0, u1);
    }
    #pragma unroll
    for (int i = 0; i < 6; i++) {
      f32x4 acc = {0.f, 0.f, 0.f, 0.f};
      #pragma unroll
      for (int ks = 0; ks < 4; ks++)
        acc = __builtin_amdgcn_mfma_f32_16x16x32_f16(afr[ks], bfr[i][ks], acc, 0, 0, 0);
      int nt = 6 * wv + i;
      int col = nt * 16 + r16;                  // 0..383
      float b = bias[i];
      float scale = (nt < 8) ? 0.25f : 1.0f;    // fold 1/sqrt(hd) into Q
      #pragma unroll
      for (int r = 0; r < 4; r++) {
        int rowl = mt * 16 + 4 * g + r;         // 0..95
        f16 h = (f16)((acc[r] + b) * scale);
        if (nt < 16) {
          *(f16*)(qkvB + swz(rowl, col * 2)) = h;         // Q (0-127) / K (128-255)
        } else {
          int dfull = (nt - 16) * 16 + r16;               // V col -> vT row
          int t = rowl / 22;
          int j = rowl - t * 22;
          vT[dfull * VT_STRIDE + t * 24 + j] = h;         // V^T, token-padded
        }
      }
    }
  }
  __syncthreads();

  // ============ Phase 2: attention; wave wv handles token wv (8 heads x 2 q-tiles) ====
  {
    const int t = wv;
    const int rbase = t * 22;
    for (int h = 0; h < 8; h++) {
      f16x4 kf[2], vf[2];
      #pragma unroll
      for (int jt = 0; jt < 2; jt++) {
        int row = rbase + jt * 16 + r16;                       // may run into next token: masked
        kf[jt] = *(const f16x4*)(qkvB + swz(row, (128 + h * 16 + 4 * g) * 2));
        vf[jt] = *(const f16x4*)(&vT[(h * 16 + r16) * VT_STRIDE + t * 24 + jt * 16 + 4 * g]);
      }
      #pragma unroll
      for (int qt = 0; qt < 2; qt++) {
        f16x4 qf = *(const f16x4*)(qkvB + swz(rbase + qt * 16 + r16, (h * 16 + 4 * g) * 2));
        // S^T = K . Q^T : lane holds S^T[j][q], q=r16, j=jt*16+4g+r
        f32x4 s0 = {0.f, 0.f, 0.f, 0.f}, s1 = {0.f, 0.f, 0.f, 0.f};
        s0 = __builtin_amdgcn_mfma_f32_16x16x16f16(kf[0], qf, s0, 0, 0, 0);
        s1 = __builtin_amdgcn_mfma_f32_16x16x16f16(kf[1], qf, s1, 0, 0, 0);
        float sv[8];
        #pragma unroll
        for (int r = 0; r < 4; r++) {
          sv[r]     = s0[r] + mreg[qt][0][r];
          sv[4 + r] = s1[r] + mreg[qt][1][r];
        }
        float mx = sv[0];
        #pragma unroll
        for (int i = 1; i < 8; i++) mx = fmaxf(mx, sv[i]);
        mx = fmaxf(mx, __shfl_xor(mx, 16, 64));
        mx = fmaxf(mx, __shfl_xor(mx, 32, 64));
        float p[8], sum = 0.f;
        #pragma unroll
        for (int i = 0; i < 8; i++) { p[i] = __expf(sv[i] - mx); sum += p[i]; }
        sum += __shfl_xor(sum, 16, 64);
        sum += __shfl_xor(sum, 32, 64);
        float inv = 1.0f / sum;
        f16x4 pb0, pb1;
        #pragma unroll
        for (int r = 0; r < 4; r++) {
          pb0[r] = (f16)(p[r] * inv);
          pb1[r] = (f16)(p[4 + r] * inv);
        }
        // y^T = V^T . P^T : P^T frag layout from scores matches PV B-frag exactly
        f32x4 ya = {0.f, 0.f, 0.f, 0.f};
        ya = __builtin_amdgcn_mfma_f32_16x16x16f16(vf[0], pb0, ya, 0, 0, 0);
        ya = __builtin_amdgcn_mfma_f32_16x16x16f16(vf[1], pb1, ya, 0, 0, 0);
        int q = qt * 16 + r16;
        if (q < 22) {                       // discard garbage queries
          f16x4 yh;
          #pragma unroll
          for (int r = 0; r < 4; r++) yh[r] = (f16)ya[r];
          // y overwrites dead Q slot: row rbase+q, cols h*16+4g..+3
          *(f16x4*)(qkvB + swz(rbase + q, (h * 16 + 4 * g) * 2)) = yh;
        }
      }
    }
  }
  __syncthreads();

  // ============ Phase 3: out projection (wave wv owns n-tiles 2wv,2wv+1 of 8) =========
  f16x8 obf[2][4];
  float ob[2];
  #pragma unroll
  for (int i = 0; i < 2; i++) {
    int nt = 2 * wv + i;
    const float* wp = wout + (nt * 16 + r16) * 128 + g * 8;
    #pragma unroll
    for (int ks = 0; ks < 4; ks++) {
      float4 u0 = *(const float4*)(wp + ks * 32);
      float4 u1 = *(const float4*)(wp + ks * 32 + 4);
      obf[i][ks] = pack8(u0, u1);
    }
    ob[i] = bout[nt * 16 + r16];
  }
  for (int mt = 0; mt < 6; mt++) {
    f16x8 afr[4];
    #pragma unroll
    for (int ks = 0; ks < 4; ks++)
      afr[ks] = *(const f16x8*)(qkvB + swz(mt * 16 + r16, (ks * 32 + g * 8) * 2));
    #pragma unroll
    for (int i = 0; i < 2; i++) {
      f32x4 acc = {0.f, 0.f, 0.f, 0.f};
      #pragma unroll
      for (int ks = 0; ks < 4; ks++)
        acc = __builtin_amdgcn_mfma_f32_16x16x32_f16(afr[ks], obf[i][ks], acc, 0, 0, 0);
      int col = (2 * wv + i) * 16 + r16;
      float b = ob[i];
      #pragma unroll
      for (int r = 0; r < 4; r++) {
        int rowl = mt * 16 + 4 * g + r;
        if (rowl < RG) out[(g0 + rowl) * 128 + col] = acc[r] + b;
      }
    }
  }
}

extern "C" void kernel_launch(void* const* d_in, const int* in_sizes, int n_in,
                              void* d_out, int out_size, void* d_ws, size_t ws_size,
                              hipStream_t stream) {
  const float* x    = (const float*)d_in[0];
  const int*   adj  = (const int*)d_in[1];
  const float* wqkv = (const float*)d_in[2];
  const float* bqkv = (const float*)d_in[3];
  const float* wout = (const float*)d_in[4];
  const float* bout = (const float*)d_in[5];
  float* o = (float*)d_out;
  mga_fused<<<dim3(NGROUPS), dim3(256), 0, stream>>>(x, adj, wqkv, bqkv, wout, bout, o);
}

// Round 2
// 260.482 us; speedup vs baseline: 1.0647x; 1.0647x over previous
//
#include <hip/hip_runtime.h>

typedef _Float16 f16;
typedef _Float16 f16x4 __attribute__((ext_vector_type(4)));
typedef _Float16 f16x8 __attribute__((ext_vector_type(8)));
typedef float f32x4 __attribute__((ext_vector_type(4)));

// B=64, T=240, J=22, D=128, H=8, hd=16; n_tokens=15360, rows=337920
#define N_ROWS   337920
#define RG       44              // 2 tokens * 22 rows per workgroup
#define NGROUPS  7680            // 15360/2
// LDS: qkv [48 rows][256 dims f16] XOR-swizzled (Q dims 0-127 -> later y, K 128-255)
//      vT  [128 dims][64 cols f16] XOR-swizzled (V transposed; col = t*32 + j)
#define QKV_ROWB  512
#define QKV_BYTES (48 * QKV_ROWB)              // 24576
#define VT_OFF    QKV_BYTES
#define LDS_BYTES (QKV_BYTES + 128 * 64 * 2)   // 40960 -> 4 WG/CU

#define WQKV_F16_ELEMS 49152                   // 384*128
#define WS_NEEDED ((49152 + 16384) * 2)        // 131072 bytes of f16 weights

__device__ __forceinline__ uint32_t swz(int row, int bytecol) {
  return (uint32_t)((row * QKV_ROWB + bytecol) ^ ((row & 7) << 4));
}
__device__ __forceinline__ uint32_t vswz(int d, int col) {
  return (uint32_t)(VT_OFF + ((d * 128 + col * 2) ^ ((d & 15) << 3)));
}

__device__ __forceinline__ f16x8 pack8(float4 a, float4 b) {
  f16x8 r;
  r[0] = (f16)a.x; r[1] = (f16)a.y; r[2] = (f16)a.z; r[3] = (f16)a.w;
  r[4] = (f16)b.x; r[5] = (f16)b.y; r[6] = (f16)b.z; r[7] = (f16)b.w;
  return r;
}

// weight fragment: f16 fast path from ws, fp32 fallback with inline cvt
__device__ __forceinline__ f16x8 ldw8(const f16* w16p, const float* w32p, int f16m) {
  if (f16m) return *(const f16x8*)w16p;
  float4 u0 = *(const float4*)w32p;
  float4 u1 = *(const float4*)(w32p + 4);
  return pack8(u0, u1);
}

__global__ void prep_w(const float* __restrict__ wqkv, const float* __restrict__ wout,
                       f16* __restrict__ w16) {
  int i4 = (blockIdx.x * 256 + threadIdx.x) * 4;   // grid 64 x 256 covers 65536
  const float* src = (i4 < WQKV_F16_ELEMS) ? (wqkv + i4) : (wout + (i4 - WQKV_F16_ELEMS));
  float4 v = *(const float4*)src;
  f16x4 h;
  h[0] = (f16)v.x; h[1] = (f16)v.y; h[2] = (f16)v.z; h[3] = (f16)v.w;
  *(f16x4*)(w16 + i4) = h;
}

__global__ __launch_bounds__(256, 4)
void mga_fused(const float* __restrict__ x, const int* __restrict__ adj,
               const float* __restrict__ bqkv, const float* __restrict__ bout,
               const f16* __restrict__ w16, const float* __restrict__ wqkv32,
               const float* __restrict__ wout32, int f16m,
               float* __restrict__ out) {
  __shared__ __align__(16) char smem[LDS_BYTES];

  const int tid = threadIdx.x;
  const int wv  = tid >> 6;
  const int l   = tid & 63;
  const int g   = l >> 4;
  const int r16 = l & 15;
  const long g0 = (long)blockIdx.x * RG;

  // ---- zero vT (cols j>=22 per token stay 0 so P==0 lanes never hit NaN) ----
  {
    int* p = (int*)(smem + VT_OFF);
    #pragma unroll
    for (int i = 0; i < 16; i++) p[tid + 256 * i] = 0;   // 16*256*4 = 16384 B
  }
  __syncthreads();

  // ============ Phase 1: QKV projection, SWAPPED operands ============
  // D = mfma(A=W rows, B=x rows): lane holds 4 consecutive DIMS at fixed row
  // -> b64 LDS writes for Q/K, dwordx4-ready layout for phase 3.
  f16x8 xf[3][4];
  #pragma unroll
  for (int mt = 0; mt < 3; mt++) {
    long rowg = g0 + mt * 16 + r16;
    if (rowg > (long)N_ROWS - 1) rowg = N_ROWS - 1;      // clamp pad rows
    const float* xp = x + rowg * 128 + g * 8;
    #pragma unroll
    for (int ks = 0; ks < 4; ks++) {
      float4 u0 = *(const float4*)(xp + ks * 32);
      float4 u1 = *(const float4*)(xp + ks * 32 + 4);
      xf[mt][ks] = pack8(u0, u1);
    }
  }

  #pragma unroll
  for (int i = 0; i < 6; i++) {
    int nt = wv + 4 * i;                 // interleaved: every wave gets 2 V-tiles
    int wrow = nt * 16 + r16;
    f16x8 wf[4];
    #pragma unroll
    for (int ks = 0; ks < 4; ks++) {
      int off = wrow * 128 + ks * 32 + g * 8;
      wf[ks] = ldw8(w16 + off, wqkv32 + off, f16m);
    }
    float4 bv = *(const float4*)(bqkv + nt * 16 + 4 * g);   // bias for 4 dims
    float scale = (nt < 8) ? 0.25f : 1.0f;                  // fold 1/sqrt(hd) into Q
    f32x4 acc[3] = {{0,0,0,0},{0,0,0,0},{0,0,0,0}};
    #pragma unroll
    for (int mt = 0; mt < 3; mt++)
      #pragma unroll
      for (int ks = 0; ks < 4; ks++)
        acc[mt] = __builtin_amdgcn_mfma_f32_16x16x32_f16(wf[ks], xf[mt][ks], acc[mt], 0, 0, 0);

    #pragma unroll
    for (int mt = 0; mt < 3; mt++) {
      int rowl = mt * 16 + r16;          // row index (n) of this lane
      if (nt < 16) {                     // Q/K: 4 consecutive dims -> one b64
        f16x4 h4;
        #pragma unroll
        for (int r = 0; r < 4; r++) h4[r] = (f16)((acc[mt][r] + ((const float*)&bv)[r]) * scale);
        *(f16x4*)(smem + swz(rowl, (nt * 16 + 4 * g) * 2)) = h4;
      } else if (rowl < RG) {            // V -> vT (transpose: 4 scalar writes)
        int t = rowl >= 22;
        int j = rowl - 22 * t;
        int col = t * 32 + j;
        int dv = (nt - 16) * 16 + 4 * g;
        #pragma unroll
        for (int r = 0; r < 4; r++)
          *(f16*)(smem + vswz(dv + r, col)) = (f16)(acc[mt][r] + ((const float*)&bv)[r]);
      }
    }
  }

  // ---- adjacency mask regs M^T[j][q] (needed only in phase 2) ----
  float mreg[2][2][4];
  #pragma unroll
  for (int qt = 0; qt < 2; qt++)
    #pragma unroll
    for (int jt = 0; jt < 2; jt++)
      #pragma unroll
      for (int r = 0; r < 4; r++) {
        int q = qt * 16 + r16;
        int j = jt * 16 + 4 * g + r;
        float m = -1e30f;
        if (j < 22) m = (q >= 22 || adj[q * 22 + j] > 0) ? 0.0f : -1e30f;
        mreg[qt][jt][r] = m;
      }

  __syncthreads();

  // ============ Phase 2: attention; wave = (token wv>>1, head-half wv&1) ============
  {
    const int t = wv >> 1;
    const int rbase = 22 * t;
    for (int hi = 0; hi < 4; hi++) {
      int h = 4 * (wv & 1) + hi;
      f16x4 kf[2], vf[2];
      #pragma unroll
      for (int jt = 0; jt < 2; jt++) {
        int rowk = rbase + jt * 16 + r16;
        if (rowk > 47) rowk = 47;                          // clamped, finite, masked
        kf[jt] = *(const f16x4*)(smem + swz(rowk, (128 + h * 16 + 4 * g) * 2));
        vf[jt] = *(const f16x4*)(smem + vswz(h * 16 + r16, t * 32 + jt * 16 + 4 * g));
      }
      #pragma unroll
      for (int qt = 0; qt < 2; qt++) {
        int rowq = rbase + qt * 16 + r16;
        if (rowq > 47) rowq = 47;
        f16x4 qf = *(const f16x4*)(smem + swz(rowq, (h * 16 + 4 * g) * 2));
        f32x4 s0 = {0.f,0.f,0.f,0.f}, s1 = {0.f,0.f,0.f,0.f};
        s0 = __builtin_amdgcn_mfma_f32_16x16x16f16(kf[0], qf, s0, 0, 0, 0);
        s1 = __builtin_amdgcn_mfma_f32_16x16x16f16(kf[1], qf, s1, 0, 0, 0);
        float sv[8];
        #pragma unroll
        for (int r = 0; r < 4; r++) {
          sv[r]     = s0[r] + mreg[qt][0][r];
          sv[4 + r] = s1[r] + mreg[qt][1][r];
        }
        float mx = sv[0];
        #pragma unroll
        for (int i = 1; i < 8; i++) mx = fmaxf(mx, sv[i]);
        mx = fmaxf(mx, __shfl_xor(mx, 16, 64));
        mx = fmaxf(mx, __shfl_xor(mx, 32, 64));
        float p[8], sum = 0.f;
        #pragma unroll
        for (int i = 0; i < 8; i++) { p[i] = __expf(sv[i] - mx); sum += p[i]; }
        sum += __shfl_xor(sum, 16, 64);
        sum += __shfl_xor(sum, 32, 64);
        float inv = 1.0f / sum;
        f16x4 pb0, pb1;
        #pragma unroll
        for (int r = 0; r < 4; r++) {
          pb0[r] = (f16)(p[r] * inv);
          pb1[r] = (f16)(p[4 + r] * inv);
        }
        f32x4 ya = {0.f,0.f,0.f,0.f};
        ya = __builtin_amdgcn_mfma_f32_16x16x16f16(vf[0], pb0, ya, 0, 0, 0);
        ya = __builtin_amdgcn_mfma_f32_16x16x16f16(vf[1], pb1, ya, 0, 0, 0);
        int q = qt * 16 + r16;
        if (q < 22) {                    // y overwrites dead Q slot (same head's dims)
          f16x4 yh;
          #pragma unroll
          for (int r = 0; r < 4; r++) yh[r] = (f16)ya[r];
          *(f16x4*)(smem + swz(rbase + q, (h * 16 + 4 * g) * 2)) = yh;
        }
      }
    }
  }
  __syncthreads();

  // ============ Phase 3: out projection, SWAPPED operands -> dwordx4 stores ========
  const f16* w16o = w16 + WQKV_F16_ELEMS;
  f16x8 wf[2][4];
  float4 bv[2];
  #pragma unroll
  for (int i = 0; i < 2; i++) {
    int nt = 2 * wv + i;
    int wrow = nt * 16 + r16;
    #pragma unroll
    for (int ks = 0; ks < 4; ks++) {
      int off = wrow * 128 + ks * 32 + g * 8;
      wf[i][ks] = ldw8(w16o + off, wout32 + off, f16m);
    }
    bv[i] = *(const float4*)(bout + nt * 16 + 4 * g);
  }
  for (int mt = 0; mt < 3; mt++) {
    f16x8 af[4];
    #pragma unroll
    for (int ks = 0; ks < 4; ks++)
      af[ks] = *(const f16x8*)(smem + swz(mt * 16 + r16, (ks * 32 + g * 8) * 2));
    int rowl = mt * 16 + r16;
    #pragma unroll
    for (int i = 0; i < 2; i++) {
      f32x4 acc = {0.f,0.f,0.f,0.f};
      #pragma unroll
      for (int ks = 0; ks < 4; ks++)
        acc = __builtin_amdgcn_mfma_f32_16x16x32_f16(wf[i][ks], af[ks], acc, 0, 0, 0);
      if (rowl < RG) {
        float4 o;
        o.x = acc[0] + bv[i].x; o.y = acc[1] + bv[i].y;
        o.z = acc[2] + bv[i].z; o.w = acc[3] + bv[i].w;
        *(float4*)(out + (g0 + rowl) * 128 + (2 * wv + i) * 16 + 4 * g) = o;
      }
    }
  }
}

extern "C" void kernel_launch(void* const* d_in, const int* in_sizes, int n_in,
                              void* d_out, int out_size, void* d_ws, size_t ws_size,
                              hipStream_t stream) {
  const float* x    = (const float*)d_in[0];
  const int*   adj  = (const int*)d_in[1];
  const float* wqkv = (const float*)d_in[2];
  const float* bqkv = (const float*)d_in[3];
  const float* wout = (const float*)d_in[4];
  const float* bout = (const float*)d_in[5];
  float* o = (float*)d_out;

  int f16m = (d_ws != nullptr && ws_size >= (size_t)WS_NEEDED) ? 1 : 0;
  f16* w16 = (f16*)d_ws;
  if (f16m) prep_w<<<dim3(64), dim3(256), 0, stream>>>(wqkv, wout, w16);
  mga_fused<<<dim3(NGROUPS), dim3(256), 0, stream>>>(x, adj, bqkv, bout,
                                                     w16, wqkv, wout, f16m, o);
}